// Round 1
// baseline (1343.730 us; speedup 1.0000x reference)
//
#include <hip/hip_runtime.h>

#define B_  8192
#define F_  50
#define E_  64
#define H_  2
#define HD_ 32
#define D_  8

static constexpr float LN_EPS = 1e-6f;
static constexpr float SCALE  = 0.17677669529663687f; // 1/sqrt(32)

__global__ __launch_bounds__(256, 2)
void mdr_fused(const float* __restrict__ x_g,
               const int*   __restrict__ dom_g,
               const float* __restrict__ wq_g,   // [D,E,E]
               const float* __restrict__ wk_g,   // [E,E]
               const float* __restrict__ wv_g,   // [E,E]
               const float* __restrict__ wr_g,   // [E,E]
               const float* __restrict__ gam_g,  // [D,E]
               const float* __restrict__ bet_g,  // [D,E]
               float* __restrict__ out_g)        // [B,F,E]
{
    __shared__ float xs[F_][E_];       // 12800 B, broadcast reads only
    __shared__ float qs[F_][68];       // stride 68: conflict-free col writes / b128 reads
    __shared__ float ks[F_][68];
    __shared__ float vs[F_][68];
    // union buffer: staged weight matrix ws[64][64] (4096 f) / scores ss[2][50][53] (5300 f)
    __shared__ __align__(16) float uni[5300];

    const int tid  = threadIdx.x;
    const int lane = tid & 63;
    const int w    = tid >> 6;       // wave id 0..3
    const int b    = blockIdx.x;

    const int idxd = dom_g[b] - 1;   // domain ids are 1..D

    // ---------------- stage x [50][64] ----------------
    {
        const float4* src = (const float4*)(x_g + (size_t)b * (F_ * E_));
        float4* dst = (float4*)&xs[0][0];
        for (int i = tid; i < F_ * E_ / 4; i += 256) dst[i] = src[i];
    }

    // ---------------- projections Q, K, V ----------------
    const float* wsrc0 = wq_g + (size_t)idxd * E_ * E_;
    for (int m = 0; m < 3; ++m) {
        __syncthreads();  // previous consumer of uni (or x-stage) done
        {
            const float* wsrc = (m == 0) ? wsrc0 : (m == 1) ? wk_g : wv_g;
            const float4* src = (const float4*)wsrc;
            float4* dst = (float4*)uni;
            for (int i = tid; i < E_ * E_ / 4; i += 256) dst[i] = src[i];
        }
        __syncthreads();
        const float (*ws)[E_] = (const float (*)[E_])uni;
        // per-lane weight column in registers
        float col[E_];
        #pragma unroll
        for (int i = 0; i < E_; ++i) col[i] = ws[i][lane];
        float (*dst)[68] = (m == 0) ? qs : (m == 1) ? ks : vs;
        for (int f = w; f < F_; f += 4) {
            float acc = 0.f;
            #pragma unroll
            for (int i4 = 0; i4 < 16; ++i4) {
                const float4 xv = *(const float4*)&xs[f][i4 * 4];
                acc += xv.x * col[i4*4+0] + xv.y * col[i4*4+1]
                     + xv.z * col[i4*4+2] + xv.w * col[i4*4+3];
            }
            dst[f][lane] = acc;
        }
    }
    __syncthreads();  // V compute done reading uni; scores may overwrite it

    // ---------------- scores: wave -> (head, j-half) ----------------
    float (*ss)[F_][53] = (float (*)[F_][53])uni;
    {
        const int h  = w >> 1;
        const int jb = (w & 1) * 25;
        const int iq = (lane < F_) ? lane : (F_ - 1);
        float qr[HD_];
        #pragma unroll
        for (int c = 0; c < HD_ / 4; ++c) {
            const float4 t4 = *(const float4*)&qs[iq][h * HD_ + c * 4];
            qr[c*4+0] = t4.x; qr[c*4+1] = t4.y; qr[c*4+2] = t4.z; qr[c*4+3] = t4.w;
        }
        for (int jj = 0; jj < 25; ++jj) {
            const int j = jb + jj;
            float acc = 0.f;
            #pragma unroll
            for (int c = 0; c < HD_ / 4; ++c) {
                const float4 kv = *(const float4*)&ks[j][h * HD_ + c * 4];
                acc += qr[c*4+0] * kv.x + qr[c*4+1] * kv.y
                     + qr[c*4+2] * kv.z + qr[c*4+3] * kv.w;
            }
            if (lane < F_) ss[h][iq][j] = acc * SCALE;
        }
    }
    __syncthreads();

    // ---------------- softmax: one row per thread (100 rows) ----------------
    if (tid < H_ * F_) {
        const int h = tid / F_, i = tid % F_;
        float* row = ss[h][i];
        float mx = -1e30f;
        for (int j = 0; j < F_; ++j) mx = fmaxf(mx, row[j]);
        float s = 0.f;
        for (int j = 0; j < F_; ++j) { const float e = __expf(row[j] - mx); s += e; row[j] = e; }
        const float r = 1.f / s;
        for (int j = 0; j < F_; ++j) row[j] *= r;
    }
    __syncthreads();

    // ---------------- PV: lane -> (fq, ec); thread owns 4 f-rows x 4 e ----------------
    const int fq = lane >> 4;
    const int ec = lane & 15;
    const int e0 = ec * 4;
    const int hh = ec >> 3;          // head of this e-chunk
    const int wf = w * 4 + fq;       // 0..15; f = fg*16 + wf

    float4 o[4];
    #pragma unroll
    for (int fg = 0; fg < 4; ++fg) { o[fg].x = 0.f; o[fg].y = 0.f; o[fg].z = 0.f; o[fg].w = 0.f; }

    for (int j = 0; j < F_; ++j) {
        const float4 vv = *(const float4*)&vs[j][e0];
        #pragma unroll
        for (int fg = 0; fg < 4; ++fg) {
            const int f = fg * 16 + wf;
            const float a = ss[hh][(f < F_) ? f : (F_ - 1)][j];
            o[fg].x += a * vv.x; o[fg].y += a * vv.y;
            o[fg].z += a * vv.z; o[fg].w += a * vv.w;
        }
    }
    __syncthreads();  // done reading ss; reuse uni for W_res

    // ---------------- residual: stage W_res, add x @ W_res ----------------
    {
        const float4* src = (const float4*)wr_g;
        float4* dst = (float4*)uni;
        for (int i = tid; i < E_ * E_ / 4; i += 256) dst[i] = src[i];
    }
    __syncthreads();
    {
        const float (*ws)[E_] = (const float (*)[E_])uni;
        for (int i4 = 0; i4 < 16; ++i4) {
            float4 wv[4];
            #pragma unroll
            for (int t = 0; t < 4; ++t) wv[t] = *(const float4*)&ws[i4 * 4 + t][e0];
            #pragma unroll
            for (int fg = 0; fg < 4; ++fg) {
                const int f = fg * 16 + wf;
                const float4 xv = *(const float4*)&xs[(f < F_) ? f : (F_ - 1)][i4 * 4];
                o[fg].x += xv.x * wv[0].x + xv.y * wv[1].x + xv.z * wv[2].x + xv.w * wv[3].x;
                o[fg].y += xv.x * wv[0].y + xv.y * wv[1].y + xv.z * wv[2].y + xv.w * wv[3].y;
                o[fg].z += xv.x * wv[0].z + xv.y * wv[1].z + xv.z * wv[2].z + xv.w * wv[3].z;
                o[fg].w += xv.x * wv[0].w + xv.y * wv[1].w + xv.z * wv[2].w + xv.w * wv[3].w;
            }
        }
    }

    // ---------------- relu + LayerNorm + store ----------------
    const float4 g4 = *(const float4*)&gam_g[idxd * E_ + e0];
    const float4 b4 = *(const float4*)&bet_g[idxd * E_ + e0];
    #pragma unroll
    for (int fg = 0; fg < 4; ++fg) {
        const int f = fg * 16 + wf;
        float4 v = o[fg];
        v.x = fmaxf(v.x, 0.f); v.y = fmaxf(v.y, 0.f);
        v.z = fmaxf(v.z, 0.f); v.w = fmaxf(v.w, 0.f);
        float s1 = v.x + v.y + v.z + v.w;
        float s2 = v.x * v.x + v.y * v.y + v.z * v.z + v.w * v.w;
        // reduce across the 16 lanes sharing this f (ec = lane&15)
        #pragma unroll
        for (int msk = 1; msk < 16; msk <<= 1) {
            s1 += __shfl_xor(s1, msk, 64);
            s2 += __shfl_xor(s2, msk, 64);
        }
        const float mean = s1 * (1.f / E_);
        const float var  = s2 * (1.f / E_) - mean * mean;
        const float rs   = rsqrtf(var + LN_EPS);
        float4 y;
        y.x = (v.x - mean) * rs * g4.x + b4.x;
        y.y = (v.y - mean) * rs * g4.y + b4.y;
        y.z = (v.z - mean) * rs * g4.z + b4.z;
        y.w = (v.w - mean) * rs * g4.w + b4.w;
        if (f < F_) *(float4*)&out_g[((size_t)b * F_ + f) * E_ + e0] = y;
    }
}

extern "C" void kernel_launch(void* const* d_in, const int* in_sizes, int n_in,
                              void* d_out, int out_size, void* d_ws, size_t ws_size,
                              hipStream_t stream) {
    const float* x   = (const float*)d_in[0];
    const int*   dom = (const int*)  d_in[1];
    const float* wq  = (const float*)d_in[2];
    const float* wk  = (const float*)d_in[3];
    const float* wv  = (const float*)d_in[4];
    const float* wr  = (const float*)d_in[5];
    const float* gam = (const float*)d_in[6];
    const float* bet = (const float*)d_in[7];
    float* out = (float*)d_out;
    hipLaunchKernelGGL(mdr_fused, dim3(B_), dim3(256), 0, stream,
                       x, dom, wq, wk, wv, wr, gam, bet, out);
}

// Round 2
// 227.369 us; speedup vs baseline: 5.9099x; 5.9099x over previous
//
#include <hip/hip_runtime.h>

#define NB    8192
#define NF    50
#define NE    64
#define ND    8
#define STR   72            // LDS row stride in bf16 elems (144 B) -> conflict-optimal b128 reads
#define GPB   4             // batch rows per block
#define GRID  (NB / GPB)

typedef __attribute__((ext_vector_type(8))) short short8;   // 8 x bf16 (4 VGPR) MFMA A/B frag
typedef __attribute__((ext_vector_type(4))) short short4v;  // 4 x bf16 packed store
typedef __attribute__((ext_vector_type(4))) float float4v;  // MFMA C/D frag

static constexpr float SCALE  = 0.17677669529663687f; // 1/sqrt(32)
static constexpr float LN_EPS = 1e-6f;

#define MFMA(a, b, c) __builtin_amdgcn_mfma_f32_16x16x32_bf16((a), (b), (c), 0, 0, 0)

__device__ __forceinline__ unsigned short bf16rne(float f) {
    unsigned int u = __builtin_bit_cast(unsigned int, f);
    return (unsigned short)((u + 0x7fffu + ((u >> 16) & 1u)) >> 16);
}

__device__ __forceinline__ void st_pack4(unsigned short* p, float4v v) {
    short4v h;
    h.x = (short)bf16rne(v.x); h.y = (short)bf16rne(v.y);
    h.z = (short)bf16rne(v.z); h.w = (short)bf16rne(v.w);
    *(short4v*)p = h;   // ds_write_b64
}

// ---- prep: transpose all weights to bf16 [mat][o][e] = W[e][o] in d_ws ----
// slots 0..7 = Wq domains, 8 = Wk, 9 = Wv, 10 = Wr
__global__ void prep_weights(const float* __restrict__ wq, const float* __restrict__ wk,
                             const float* __restrict__ wv, const float* __restrict__ wr,
                             unsigned short* __restrict__ ws) {
    int i = blockIdx.x * 256 + threadIdx.x;
    if (i >= 11 * 4096) return;
    int m = i >> 12, t = i & 4095, o = t >> 6, e = t & 63;
    float v;
    if (m < 8)       v = wq[(m * 64 + e) * 64 + o];
    else if (m == 8) v = wk[e * 64 + o];
    else if (m == 9) v = wv[e * 64 + o];
    else             v = wr[e * 64 + o];
    ws[i] = bf16rne(v);
}

__global__ __launch_bounds__(256, 2)
void mdr_mfma(const float* __restrict__ x_g, const int* __restrict__ dom_g,
              const unsigned short* __restrict__ ws,
              const float* __restrict__ gam_g, const float* __restrict__ bet_g,
              float* __restrict__ out_g) {
    __shared__ unsigned short L[4 * NE * STR];   // 36864 B
    unsigned short* xs = L;                 // x rowmajor [64][STR]   (later: P head 0)
    unsigned short* Qb = L + NE * STR;      // Q rowmajor [f][e]      (later: P head 1)
    unsigned short* Kb = L + 2 * NE * STR;  // K rowmajor [f][e]
    unsigned short* Vt = L + 3 * NE * STR;  // V^T [e][f]

    const int tid = threadIdx.x;
    const int lm  = tid & 15;        // lane & 15
    const int lg  = (tid >> 4) & 3;  // lane >> 4 within wave
    const int w   = tid >> 6;        // wave 0..3

    for (int rr = 0; rr < GPB; ++rr) {
        const int b = blockIdx.x * GPB + rr;
        __syncthreads();  // prior iteration's PV LDS reads complete

        // ---------------- stage x (f32 -> bf16, rows >= NF zeroed) ----------------
        {
            const float* xb = x_g + (size_t)b * (NF * NE);
            #pragma unroll
            for (int it = 0; it < 4; ++it) {
                int s = tid + it * 256;          // 0..1023 : row = s>>4, c4 = s&15
                int r = s >> 4, c4 = s & 15;
                float4v v = {0.f, 0.f, 0.f, 0.f};
                if (r < NF) v = *(const float4v*)(xb + s * 4);
                st_pack4(xs + r * STR + c4 * 4, v);
            }
        }
        __syncthreads();
        const int dom = dom_g[b] - 1;

        // ---------------- x fragments (shared by all projections) ----------------
        short8 xf[4][2];
        #pragma unroll
        for (int t = 0; t < 4; ++t)
            #pragma unroll
            for (int ks = 0; ks < 2; ++ks)
                xf[t][ks] = *(const short8*)(xs + (lm + 16 * t) * STR + 8 * lg + 32 * ks);

        // ---------------- Q^T = Wq^T x^T  (write rowmajor Q) ----------------
        {
            const unsigned short* wq = ws + dom * 4096;
            short8 qw[4][2];
            #pragma unroll
            for (int mt = 0; mt < 4; ++mt)
                #pragma unroll
                for (int ks = 0; ks < 2; ++ks)
                    qw[mt][ks] = *(const short8*)(wq + (lm + 16 * mt) * 64 + 8 * lg + 32 * ks);
            #pragma unroll
            for (int mt = 0; mt < 4; ++mt) {
                float4v acc = {0.f, 0.f, 0.f, 0.f};
                acc = MFMA(qw[mt][0], xf[w][0], acc);
                acc = MFMA(qw[mt][1], xf[w][1], acc);
                st_pack4(Qb + (lm + 16 * w) * STR + 16 * mt + 4 * lg, acc);
            }
        }
        // ---------------- K^T = Wk^T x^T  (write rowmajor K) ----------------
        {
            const unsigned short* wk = ws + 8 * 4096;
            short8 kw[4][2];
            #pragma unroll
            for (int mt = 0; mt < 4; ++mt)
                #pragma unroll
                for (int ks = 0; ks < 2; ++ks)
                    kw[mt][ks] = *(const short8*)(wk + (lm + 16 * mt) * 64 + 8 * lg + 32 * ks);
            #pragma unroll
            for (int mt = 0; mt < 4; ++mt) {
                float4v acc = {0.f, 0.f, 0.f, 0.f};
                acc = MFMA(kw[mt][0], xf[w][0], acc);
                acc = MFMA(kw[mt][1], xf[w][1], acc);
                st_pack4(Kb + (lm + 16 * w) * STR + 16 * mt + 4 * lg, acc);
            }
        }
        // ---------------- V = x Wv  (write V^T [e][f]) ----------------
        {
            const unsigned short* wv = ws + 9 * 4096;
            short8 vw[2];
            #pragma unroll
            for (int ks = 0; ks < 2; ++ks)
                vw[ks] = *(const short8*)(wv + (lm + 16 * w) * 64 + 8 * lg + 32 * ks);
            #pragma unroll
            for (int mt = 0; mt < 4; ++mt) {
                float4v acc = {0.f, 0.f, 0.f, 0.f};
                acc = MFMA(xf[mt][0], vw[0], acc);
                acc = MFMA(xf[mt][1], vw[1], acc);
                st_pack4(Vt + (lm + 16 * w) * STR + 16 * mt + 4 * lg, acc);
            }
        }
        // ---------------- R = x Wr  (kept in registers; wave owns f-tile w) ----------------
        float4v racc[4];
        {
            const unsigned short* wr = ws + 10 * 4096;
            #pragma unroll
            for (int nt = 0; nt < 4; ++nt) {
                short8 rw0 = *(const short8*)(wr + (lm + 16 * nt) * 64 + 8 * lg);
                short8 rw1 = *(const short8*)(wr + (lm + 16 * nt) * 64 + 8 * lg + 32);
                float4v acc = {0.f, 0.f, 0.f, 0.f};
                acc = MFMA(xf[w][0], rw0, acc);
                acc = MFMA(xf[w][1], rw1, acc);
                racc[nt] = acc;
            }
        }
        __syncthreads();  // Q/K/Vt written

        // ---------------- scores: wave -> (head h, f-half fh); S^T = K Q^T ----------------
        const int h = w & 1, fh = w >> 1;
        short8 kf[4], qf[2];
        #pragma unroll
        for (int mt = 0; mt < 4; ++mt)
            kf[mt] = *(const short8*)(Kb + (lm + 16 * mt) * STR + 32 * h + 8 * lg);
        #pragma unroll
        for (int q = 0; q < 2; ++q)
            qf[q] = *(const short8*)(Qb + (lm + 16 * (2 * fh + q)) * STR + 32 * h + 8 * lg);
        __syncthreads();  // all frag loads done -> safe to overwrite xs(P0)/Qb(P1)

        float4v sacc[4][2];
        #pragma unroll
        for (int mt = 0; mt < 4; ++mt)
            #pragma unroll
            for (int q = 0; q < 2; ++q) {
                float4v z = {0.f, 0.f, 0.f, 0.f};
                sacc[mt][q] = MFMA(kf[mt], qf[q], z);
            }

        // softmax over j (rows of S^T): per-lane 16 vals + shfl_xor(16,32)
        #pragma unroll
        for (int q = 0; q < 2; ++q) {
            float p[4][4];
            float mx = -1e30f;
            #pragma unroll
            for (int mt = 0; mt < 4; ++mt)
                #pragma unroll
                for (int r = 0; r < 4; ++r) {
                    float s = sacc[mt][q][r] * SCALE;
                    if (16 * mt + 4 * lg + r >= NF) s = -1e30f;
                    p[mt][r] = s;
                    mx = fmaxf(mx, s);
                }
            mx = fmaxf(mx, __shfl_xor(mx, 16));
            mx = fmaxf(mx, __shfl_xor(mx, 32));
            float sum = 0.f;
            #pragma unroll
            for (int mt = 0; mt < 4; ++mt)
                #pragma unroll
                for (int r = 0; r < 4; ++r) {
                    float e = __expf(p[mt][r] - mx);
                    p[mt][r] = e; sum += e;
                }
            sum += __shfl_xor(sum, 16);
            sum += __shfl_xor(sum, 32);
            const float ri = 1.f / sum;
            unsigned short* Pb = h ? Qb : xs;
            #pragma unroll
            for (int mt = 0; mt < 4; ++mt) {
                float4v pv;
                pv.x = p[mt][0] * ri; pv.y = p[mt][1] * ri;
                pv.z = p[mt][2] * ri; pv.w = p[mt][3] * ri;
                st_pack4(Pb + (lm + 16 * (2 * fh + q)) * STR + 16 * mt + 4 * lg, pv);
            }
        }
        __syncthreads();  // P written

        // ---------------- PV (+R as C-init): wave owns f-tile w ----------------
        float4v oacc[4];
        #pragma unroll
        for (int c = 0; c < 4; ++c) oacc[c] = racc[c];
        #pragma unroll
        for (int hh = 0; hh < 2; ++hh) {
            const unsigned short* Pb = hh ? Qb : xs;
            short8 pf0 = *(const short8*)(Pb + (lm + 16 * w) * STR + 8 * lg);
            short8 pf1 = *(const short8*)(Pb + (lm + 16 * w) * STR + 8 * lg + 32);
            #pragma unroll
            for (int nt2 = 0; nt2 < 2; ++nt2) {
                const int c = 2 * hh + nt2;
                short8 vf0 = *(const short8*)(Vt + (32 * hh + 16 * nt2 + lm) * STR + 8 * lg);
                short8 vf1 = *(const short8*)(Vt + (32 * hh + 16 * nt2 + lm) * STR + 8 * lg + 32);
                oacc[c] = MFMA(pf0, vf0, oacc[c]);
                oacc[c] = MFMA(pf1, vf1, oacc[c]);
            }
        }

        // ---------------- relu + LayerNorm + store ----------------
        float gm[4], bt[4];
        #pragma unroll
        for (int c = 0; c < 4; ++c) {
            gm[c] = gam_g[dom * 64 + 16 * c + lm];
            bt[c] = bet_g[dom * 64 + 16 * c + lm];
        }
        #pragma unroll
        for (int r = 0; r < 4; ++r) {
            float v[4];
            #pragma unroll
            for (int c = 0; c < 4; ++c) v[c] = fmaxf(oacc[c][r], 0.f);
            float s1 = v[0] + v[1] + v[2] + v[3];
            float s2 = v[0]*v[0] + v[1]*v[1] + v[2]*v[2] + v[3]*v[3];
            #pragma unroll
            for (int msk = 1; msk < 16; msk <<= 1) {
                s1 += __shfl_xor(s1, msk);
                s2 += __shfl_xor(s2, msk);
            }
            const float mean = s1 * (1.f / 64.f);
            const float var  = s2 * (1.f / 64.f) - mean * mean;
            const float rs   = rsqrtf(var + LN_EPS);
            const int f = 4 * lg + r + 16 * w;
            if (f < NF) {
                float* op = out_g + (size_t)b * (NF * NE) + f * 64 + lm;
                #pragma unroll
                for (int c = 0; c < 4; ++c)
                    op[16 * c] = (v[c] - mean) * rs * gm[c] + bt[c];
            }
        }
    }
}

extern "C" void kernel_launch(void* const* d_in, const int* in_sizes, int n_in,
                              void* d_out, int out_size, void* d_ws, size_t ws_size,
                              hipStream_t stream) {
    const float* x   = (const float*)d_in[0];
    const int*   dom = (const int*)  d_in[1];
    const float* wq  = (const float*)d_in[2];
    const float* wk  = (const float*)d_in[3];
    const float* wv  = (const float*)d_in[4];
    const float* wr  = (const float*)d_in[5];
    const float* gam = (const float*)d_in[6];
    const float* bet = (const float*)d_in[7];
    unsigned short* ws = (unsigned short*)d_ws;
    float* out = (float*)d_out;

    hipLaunchKernelGGL(prep_weights, dim3(176), dim3(256), 0, stream, wq, wk, wv, wr, ws);
    hipLaunchKernelGGL(mdr_mfma, dim3(GRID), dim3(256), 0, stream,
                       x, dom, ws, gam, bet, out);
}